// Round 1
// baseline (5696.980 us; speedup 1.0000x reference)
//
#include <hip/hip_runtime.h>
#include <math.h>

#define TT   2048   // tokens
#define HH   2048   // hidden
#define IE   512    // expert inter
#define SIE  1024   // shared inter
#define NE   64     // experts
#define TOPK 8

#define TS   128    // expert M tile (pairs)
#define TSS  64     // shared M tile (tokens)
#define NC   128    // N chunk
#define KB   32     // K block
#define KS   40     // LDS k-stride in bf16 elems (32 + 8 pad, 80 B = 16B-aligned)

typedef __attribute__((ext_vector_type(8))) short short8;
typedef __attribute__((ext_vector_type(4))) float f32x4;

__device__ __forceinline__ unsigned short f2bf(float f) {
  unsigned int u = __float_as_uint(f);
  u += 0x7FFF + ((u >> 16) & 1);   // RNE
  return (unsigned short)(u >> 16);
}

// ---------------------------------------------------------------- router
// fp32 logits (top-k selection is numerically knife-edged; bf16 would flip
// selections vs the np reference). 8 tokens/block, 256 blocks.
__global__ __launch_bounds__(256) void k_router(
    const float* __restrict__ x, const float* __restrict__ rw,
    int* __restrict__ cnt, int* __restrict__ list, float* __restrict__ wtb)
{
  __shared__ float rwS[64 * 65];   // stride 65: conflict-free column reads
  __shared__ float xs[8 * 68];
  const int tid  = threadIdx.x;
  const int lane = tid & 63;       // = expert index
  const int g    = tid >> 6;       // wave id, owns tokens g*2, g*2+1
  const int t0   = blockIdx.x * 8;

  float part0 = 0.f, part1 = 0.f;
  for (int h0 = 0; h0 < HH; h0 += 64) {
    {
      const int e = tid >> 2, c = (tid & 3) * 16;
      const float* src = rw + (size_t)e * HH + h0 + c;
      #pragma unroll
      for (int u = 0; u < 4; ++u) {
        float4 v = *(const float4*)(src + u * 4);
        float* dst = &rwS[e * 65 + c + u * 4];
        dst[0] = v.x; dst[1] = v.y; dst[2] = v.z; dst[3] = v.w;
      }
    }
    if (tid < 128) {
      const int tl = tid >> 4, c = (tid & 15) * 4;
      *(float4*)&xs[tl * 68 + c] =
          *(const float4*)(x + (size_t)(t0 + tl) * HH + h0 + c);
    }
    __syncthreads();
    const float* rrow = &rwS[lane * 65];
    const float* x0 = &xs[(g * 2 + 0) * 68];
    const float* x1 = &xs[(g * 2 + 1) * 68];
    #pragma unroll 8
    for (int j = 0; j < 64; ++j) {
      float rv = rrow[j];
      part0 = fmaf(x0[j], rv, part0);
      part1 = fmaf(x1[j], rv, part1);
    }
    __syncthreads();
  }

  for (int it = 0; it < 2; ++it) {
    const int t = t0 + g * 2 + it;
    float v = (it == 0) ? part0 : part1;
    float m = v;
    #pragma unroll
    for (int off = 32; off; off >>= 1) m = fmaxf(m, __shfl_xor(m, off));
    float p = expf(v - m);
    float s = p;
    #pragma unroll
    for (int off = 32; off; off >>= 1) s += __shfl_xor(s, off);
    p /= s;

    float pv = p, wsum = 0.f, myw = 0.f;
    int mye = 0;
    #pragma unroll
    for (int k = 0; k < TOPK; ++k) {
      float bv = pv; int bl = lane;
      #pragma unroll
      for (int off = 32; off; off >>= 1) {
        float ov = __shfl_xor(bv, off);
        int   ol = __shfl_xor(bl, off);
        if (ov > bv || (ov == bv && ol < bl)) { bv = ov; bl = ol; }
      }
      wsum += bv;
      if (lane == k)  { myw = bv; mye = bl; }
      if (lane == bl) pv = -1.f;     // remove winner
    }
    if (lane < TOPK) {
      wtb[t * TOPK + lane] = myw / wsum;
      int pos = atomicAdd(&cnt[mye], 1);
      list[mye * TT + pos] = t * TOPK + lane;   // pair id = t*8 + slot
    }
  }
}

// ------------------------------------------------------- expert gate/up
// Grouped GEMM: per (expert, 128-pair tile): P = silu(X Wg) * (X Wu) * w
__global__ __launch_bounds__(256) void k_gateup(
    const float* __restrict__ x, const float* __restrict__ wg, const float* __restrict__ wu,
    const int* __restrict__ cnt, const int* __restrict__ list, const float* __restrict__ wtb,
    unsigned short* __restrict__ P)
{
  const int e  = blockIdx.x >> 4;
  const int mt = blockIdx.x & 15;
  const int ne = cnt[e];
  const int m0 = mt * TS;
  if (m0 >= ne) return;

  __shared__ unsigned short As[TS * KS];
  __shared__ unsigned short Bg[NC * KS];
  __shared__ unsigned short Bu[NC * KS];
  __shared__ int   s_pair[TS];
  __shared__ int   s_tok[TS];
  __shared__ float s_w[TS];

  const int tid = threadIdx.x;
  if (tid < TS) {
    int idx = m0 + tid;
    int cl  = idx < ne ? idx : (ne - 1);
    int pr  = list[e * TT + cl];
    s_pair[tid] = pr;
    s_tok[tid]  = pr >> 3;
    s_w[tid]    = wtb[pr];
  }
  __syncthreads();

  const int lane = tid & 63, wv = tid >> 6, lm = lane & 15, lq = lane >> 4;
  const int ar = tid >> 1, ac = (tid & 1) * 16;
  const size_t wbase = (size_t)e * HH * IE;
  const f32x4 zero = {0.f, 0.f, 0.f, 0.f};

  for (int nc = 0; nc < 4; ++nc) {
    const int n0 = nc * NC;
    f32x4 accg[2][8], accu[2][8];
    #pragma unroll
    for (int i = 0; i < 2; ++i)
      #pragma unroll
      for (int j = 0; j < 8; ++j) { accg[i][j] = zero; accu[i][j] = zero; }

    for (int kb = 0; kb < HH / KB; ++kb) {
      const int k0 = kb * KB;
      { // A: x rows -> bf16 [m][k]
        const float* src = x + (size_t)s_tok[ar] * HH + k0 + ac;
        float4 v0 = *(const float4*)(src);
        float4 v1 = *(const float4*)(src + 4);
        float4 v2 = *(const float4*)(src + 8);
        float4 v3 = *(const float4*)(src + 12);
        short8 t0v, t1v;
        t0v[0]=f2bf(v0.x); t0v[1]=f2bf(v0.y); t0v[2]=f2bf(v0.z); t0v[3]=f2bf(v0.w);
        t0v[4]=f2bf(v1.x); t0v[5]=f2bf(v1.y); t0v[6]=f2bf(v1.z); t0v[7]=f2bf(v1.w);
        t1v[0]=f2bf(v2.x); t1v[1]=f2bf(v2.y); t1v[2]=f2bf(v2.z); t1v[3]=f2bf(v2.w);
        t1v[4]=f2bf(v3.x); t1v[5]=f2bf(v3.y); t1v[6]=f2bf(v3.z); t1v[7]=f2bf(v3.w);
        *(short8*)&As[ar * KS + ac]     = t0v;
        *(short8*)&As[ar * KS + ac + 8] = t1v;
      }
      #pragma unroll
      for (int c = 0; c < 4; ++c) { // B: [k][n] -> LDS [n][k] (transpose)
        const int f4 = c * 256 + tid;
        const int kl = f4 >> 5;
        const int n4 = (f4 & 31) * 4;
        const size_t go = wbase + (size_t)(k0 + kl) * IE + n0 + n4;
        float4 vg = *(const float4*)(wg + go);
        float4 vu = *(const float4*)(wu + go);
        Bg[(n4+0)*KS + kl] = f2bf(vg.x); Bg[(n4+1)*KS + kl] = f2bf(vg.y);
        Bg[(n4+2)*KS + kl] = f2bf(vg.z); Bg[(n4+3)*KS + kl] = f2bf(vg.w);
        Bu[(n4+0)*KS + kl] = f2bf(vu.x); Bu[(n4+1)*KS + kl] = f2bf(vu.y);
        Bu[(n4+2)*KS + kl] = f2bf(vu.z); Bu[(n4+3)*KS + kl] = f2bf(vu.w);
      }
      __syncthreads();
      short8 a0 = *(short8*)&As[(wv*32 +      lm) * KS + lq*8];
      short8 a1 = *(short8*)&As[(wv*32 + 16 + lm) * KS + lq*8];
      #pragma unroll
      for (int nt = 0; nt < 8; ++nt) {
        short8 bg = *(short8*)&Bg[(nt*16 + lm) * KS + lq*8];
        short8 bu = *(short8*)&Bu[(nt*16 + lm) * KS + lq*8];
        accg[0][nt] = __builtin_amdgcn_mfma_f32_16x16x32_bf16(a0, bg, accg[0][nt], 0, 0, 0);
        accg[1][nt] = __builtin_amdgcn_mfma_f32_16x16x32_bf16(a1, bg, accg[1][nt], 0, 0, 0);
        accu[0][nt] = __builtin_amdgcn_mfma_f32_16x16x32_bf16(a0, bu, accu[0][nt], 0, 0, 0);
        accu[1][nt] = __builtin_amdgcn_mfma_f32_16x16x32_bf16(a1, bu, accu[1][nt], 0, 0, 0);
      }
      __syncthreads();
    }
    #pragma unroll
    for (int mg = 0; mg < 2; ++mg)
      #pragma unroll
      for (int nt = 0; nt < 8; ++nt)
        #pragma unroll
        for (int r4 = 0; r4 < 4; ++r4) {
          int row = wv*32 + mg*16 + lq*4 + r4;   // C/D: row=(lane>>4)*4+reg
          if (m0 + row < ne) {
            float gg = accg[mg][nt][r4];
            float uu = accu[mg][nt][r4];
            float sv = gg / (1.f + expf(-gg)) * uu * s_w[row];
            P[(size_t)s_pair[row] * IE + n0 + nt*16 + lm] = f2bf(sv);
          }
        }
  }
}

// --------------------------------------------------------- expert down
__global__ __launch_bounds__(256) void k_down(
    const unsigned short* __restrict__ P, const float* __restrict__ wd,
    const int* __restrict__ cnt, const int* __restrict__ list,
    float* __restrict__ out)
{
  const int e  = blockIdx.x >> 4;
  const int mt = blockIdx.x & 15;
  const int ne = cnt[e];
  const int m0 = mt * TS;
  if (m0 >= ne) return;

  __shared__ unsigned short As[TS * KS];
  __shared__ unsigned short Bt[NC * KS];
  __shared__ int s_pair[TS];
  __shared__ int s_tok[TS];

  const int tid = threadIdx.x;
  if (tid < TS) {
    int idx = m0 + tid;
    int cl  = idx < ne ? idx : (ne - 1);
    int pr  = list[e * TT + cl];
    s_pair[tid] = pr;
    s_tok[tid]  = pr >> 3;
  }
  __syncthreads();

  const int lane = tid & 63, wv = tid >> 6, lm = lane & 15, lq = lane >> 4;
  const int ar = tid >> 1, ac = (tid & 1) * 16;
  const size_t wbase = (size_t)e * IE * HH;
  const f32x4 zero = {0.f, 0.f, 0.f, 0.f};

  for (int nc = 0; nc < 16; ++nc) {
    const int n0 = nc * NC;
    f32x4 acc[2][8];
    #pragma unroll
    for (int i = 0; i < 2; ++i)
      #pragma unroll
      for (int j = 0; j < 8; ++j) acc[i][j] = zero;

    for (int kb = 0; kb < IE / KB; ++kb) {
      const int k0 = kb * KB;
      { // A: P rows already bf16
        const unsigned short* src = P + (size_t)s_pair[ar] * IE + k0 + ac;
        *(short8*)&As[ar*KS + ac]     = *(const short8*)(src);
        *(short8*)&As[ar*KS + ac + 8] = *(const short8*)(src + 8);
      }
      #pragma unroll
      for (int c = 0; c < 4; ++c) {
        const int f4 = c * 256 + tid;
        const int kl = f4 >> 5;
        const int n4 = (f4 & 31) * 4;
        float4 v = *(const float4*)(wd + wbase + (size_t)(k0 + kl) * HH + n0 + n4);
        Bt[(n4+0)*KS + kl] = f2bf(v.x); Bt[(n4+1)*KS + kl] = f2bf(v.y);
        Bt[(n4+2)*KS + kl] = f2bf(v.z); Bt[(n4+3)*KS + kl] = f2bf(v.w);
      }
      __syncthreads();
      short8 a0 = *(short8*)&As[(wv*32 +      lm) * KS + lq*8];
      short8 a1 = *(short8*)&As[(wv*32 + 16 + lm) * KS + lq*8];
      #pragma unroll
      for (int nt = 0; nt < 8; ++nt) {
        short8 b = *(short8*)&Bt[(nt*16 + lm) * KS + lq*8];
        acc[0][nt] = __builtin_amdgcn_mfma_f32_16x16x32_bf16(a0, b, acc[0][nt], 0, 0, 0);
        acc[1][nt] = __builtin_amdgcn_mfma_f32_16x16x32_bf16(a1, b, acc[1][nt], 0, 0, 0);
      }
      __syncthreads();
    }
    #pragma unroll
    for (int mg = 0; mg < 2; ++mg)
      #pragma unroll
      for (int nt = 0; nt < 8; ++nt)
        #pragma unroll
        for (int r4 = 0; r4 < 4; ++r4) {
          int row = wv*32 + mg*16 + lq*4 + r4;
          if (m0 + row < ne)
            atomicAdd(&out[(size_t)s_tok[row] * HH + n0 + nt*16 + lm],
                      acc[mg][nt][r4]);
        }
  }
}

// ------------------------------------------------------ shared gate/up
__global__ __launch_bounds__(256) void k_sgateup(
    const float* __restrict__ x, const float* __restrict__ sg, const float* __restrict__ su,
    unsigned short* __restrict__ Ps)
{
  const int mt  = blockIdx.x >> 3;   // 0..31
  const int ncb = blockIdx.x & 7;    // 0..7
  const int m0 = mt * TSS, n0 = ncb * NC;

  __shared__ unsigned short As[TSS * KS];
  __shared__ unsigned short Bg[NC * KS];
  __shared__ unsigned short Bu[NC * KS];

  const int tid = threadIdx.x;
  const int lane = tid & 63, wv = tid >> 6, lm = lane & 15, lq = lane >> 4;
  const int ar = tid >> 2, ac = (tid & 3) * 8;
  const f32x4 zero = {0.f, 0.f, 0.f, 0.f};

  f32x4 accg[8], accu[8];
  #pragma unroll
  for (int j = 0; j < 8; ++j) { accg[j] = zero; accu[j] = zero; }

  for (int kb = 0; kb < HH / KB; ++kb) {
    const int k0 = kb * KB;
    {
      const float* src = x + (size_t)(m0 + ar) * HH + k0 + ac;
      float4 v0 = *(const float4*)(src);
      float4 v1 = *(const float4*)(src + 4);
      short8 tv;
      tv[0]=f2bf(v0.x); tv[1]=f2bf(v0.y); tv[2]=f2bf(v0.z); tv[3]=f2bf(v0.w);
      tv[4]=f2bf(v1.x); tv[5]=f2bf(v1.y); tv[6]=f2bf(v1.z); tv[7]=f2bf(v1.w);
      *(short8*)&As[ar * KS + ac] = tv;
    }
    #pragma unroll
    for (int c = 0; c < 4; ++c) {
      const int f4 = c * 256 + tid;
      const int kl = f4 >> 5;
      const int n4 = (f4 & 31) * 4;
      const size_t go = (size_t)(k0 + kl) * SIE + n0 + n4;
      float4 vg = *(const float4*)(sg + go);
      float4 vu = *(const float4*)(su + go);
      Bg[(n4+0)*KS + kl] = f2bf(vg.x); Bg[(n4+1)*KS + kl] = f2bf(vg.y);
      Bg[(n4+2)*KS + kl] = f2bf(vg.z); Bg[(n4+3)*KS + kl] = f2bf(vg.w);
      Bu[(n4+0)*KS + kl] = f2bf(vu.x); Bu[(n4+1)*KS + kl] = f2bf(vu.y);
      Bu[(n4+2)*KS + kl] = f2bf(vu.z); Bu[(n4+3)*KS + kl] = f2bf(vu.w);
    }
    __syncthreads();
    short8 a = *(short8*)&As[(wv*16 + lm) * KS + lq*8];
    #pragma unroll
    for (int nt = 0; nt < 8; ++nt) {
      short8 bg = *(short8*)&Bg[(nt*16 + lm) * KS + lq*8];
      short8 bu = *(short8*)&Bu[(nt*16 + lm) * KS + lq*8];
      accg[nt] = __builtin_amdgcn_mfma_f32_16x16x32_bf16(a, bg, accg[nt], 0, 0, 0);
      accu[nt] = __builtin_amdgcn_mfma_f32_16x16x32_bf16(a, bu, accu[nt], 0, 0, 0);
    }
    __syncthreads();
  }
  #pragma unroll
  for (int nt = 0; nt < 8; ++nt)
    #pragma unroll
    for (int r4 = 0; r4 < 4; ++r4) {
      int row = wv*16 + lq*4 + r4;
      float gg = accg[nt][r4], uu = accu[nt][r4];
      float sv = gg / (1.f + expf(-gg)) * uu;
      Ps[(size_t)(m0 + row) * SIE + n0 + nt*16 + lm] = f2bf(sv);
    }
}

// ------------------------------------------- shared down + final output
__global__ __launch_bounds__(256) void k_sdown(
    const unsigned short* __restrict__ Ps, const float* __restrict__ sd,
    float* __restrict__ out)
{
  const int mt  = blockIdx.x >> 4;   // 0..31
  const int ncb = blockIdx.x & 15;   // 0..15
  const int m0 = mt * TSS, n0 = ncb * NC;

  __shared__ unsigned short As[TSS * KS];
  __shared__ unsigned short Bt[NC * KS];

  const int tid = threadIdx.x;
  const int lane = tid & 63, wv = tid >> 6, lm = lane & 15, lq = lane >> 4;
  const int ar = tid >> 2, ac = (tid & 3) * 8;
  const f32x4 zero = {0.f, 0.f, 0.f, 0.f};

  f32x4 acc[8];
  #pragma unroll
  for (int j = 0; j < 8; ++j) acc[j] = zero;

  for (int kb = 0; kb < SIE / KB; ++kb) {
    const int k0 = kb * KB;
    *(short8*)&As[ar * KS + ac] =
        *(const short8*)(Ps + (size_t)(m0 + ar) * SIE + k0 + ac);
    #pragma unroll
    for (int c = 0; c < 4; ++c) {
      const int f4 = c * 256 + tid;
      const int kl = f4 >> 5;
      const int n4 = (f4 & 31) * 4;
      float4 v = *(const float4*)(sd + (size_t)(k0 + kl) * HH + n0 + n4);
      Bt[(n4+0)*KS + kl] = f2bf(v.x); Bt[(n4+1)*KS + kl] = f2bf(v.y);
      Bt[(n4+2)*KS + kl] = f2bf(v.z); Bt[(n4+3)*KS + kl] = f2bf(v.w);
    }
    __syncthreads();
    short8 a = *(short8*)&As[(wv*16 + lm) * KS + lq*8];
    #pragma unroll
    for (int nt = 0; nt < 8; ++nt) {
      short8 b = *(short8*)&Bt[(nt*16 + lm) * KS + lq*8];
      acc[nt] = __builtin_amdgcn_mfma_f32_16x16x32_bf16(a, b, acc[nt], 0, 0, 0);
    }
    __syncthreads();
  }
  #pragma unroll
  for (int nt = 0; nt < 8; ++nt)
    #pragma unroll
    for (int r4 = 0; r4 < 4; ++r4) {
      int row = wv*16 + lq*4 + r4;
      size_t idx = (size_t)(m0 + row) * HH + n0 + nt*16 + lm;
      out[idx] = out[idx] + acc[nt][r4];   // experts already accumulated
    }
}

// ---------------------------------------------------------------- launch
extern "C" void kernel_launch(void* const* d_in, const int* in_sizes, int n_in,
                              void* d_out, int out_size, void* d_ws, size_t ws_size,
                              hipStream_t stream)
{
  const float* x  = (const float*)d_in[0];
  const float* rw = (const float*)d_in[1];
  const float* wg = (const float*)d_in[2];
  const float* wu = (const float*)d_in[3];
  const float* wd = (const float*)d_in[4];
  const float* sg = (const float*)d_in[5];
  const float* su = (const float*)d_in[6];
  const float* sd = (const float*)d_in[7];
  float* out = (float*)d_out;

  // workspace layout (21.6 MB total)
  char* ws = (char*)d_ws;
  int*   cnt  = (int*)ws;                                   // 1024 B
  int*   list = (int*)(ws + 1024);                          // 64*2048*4
  float* wtb  = (float*)(ws + 1024 + (size_t)NE*TT*4);      // 2048*8*4
  unsigned short* P  = (unsigned short*)(ws + 1024 + (size_t)NE*TT*4 + (size_t)TT*TOPK*4);
  unsigned short* Ps = (unsigned short*)((char*)P + (size_t)TT*TOPK*IE*2);

  hipMemsetAsync(d_out, 0, (size_t)out_size * sizeof(float), stream);
  hipMemsetAsync(cnt, 0, 1024, stream);

  k_router <<<TT/8,               256, 0, stream>>>(x, rw, cnt, list, wtb);
  k_gateup <<<NE*(TT/TS),         256, 0, stream>>>(x, wg, wu, cnt, list, wtb, P);
  k_down   <<<NE*(TT/TS),         256, 0, stream>>>(P, wd, cnt, list, out);
  k_sgateup<<<(TT/TSS)*(SIE/NC),  256, 0, stream>>>(x, sg, su, Ps);
  k_sdown  <<<(TT/TSS)*(HH/NC),   256, 0, stream>>>(Ps, sd, out);
}